// Round 4
// baseline (157.044 us; speedup 1.0000x reference)
//
#include <hip/hip_runtime.h>

#define N 4096
#define D 1024
#define BM 128
#define BN 128
#define BK 32
#define NSLOT 32   // N / BM partial-slots per column
#define NTRI 528   // 32*33/2 lower-triangle blocks

typedef __bf16 bf16x8 __attribute__((ext_vector_type(8)));
typedef float floatx4 __attribute__((ext_vector_type(4)));

__device__ __forceinline__ ushort f2bf(float f) {
    union { float f; uint32_t u; } c; c.f = f;
    uint32_t u = c.u;
    uint32_t r = u + 0x7FFFu + ((u >> 16) & 1u);
    return (ushort)(r >> 16);
}

// ---------------------------------------------------------------------------
// Kernel 1: fp32 -> bf16 + per-row squared norm. One wave per row, no LDS.
// ---------------------------------------------------------------------------
__global__ __launch_bounds__(256) void prep_kernel(const float* __restrict__ x,
                                                   ushort* __restrict__ xb,
                                                   float* __restrict__ sq) {
    int row = blockIdx.x * 4 + (threadIdx.x >> 6);
    int lane = threadIdx.x & 63;
    const float4* xr = (const float4*)(x + (size_t)row * D);
    ushort4* br = (ushort4*)(xb + (size_t)row * D);
    float s = 0.f;
    #pragma unroll
    for (int j = 0; j < 4; ++j) {
        float4 v = xr[j * 64 + lane];
        s += v.x * v.x + v.y * v.y + v.z * v.z + v.w * v.w;
        br[j * 64 + lane] = make_ushort4(f2bf(v.x), f2bf(v.y), f2bf(v.z), f2bf(v.w));
    }
    #pragma unroll
    for (int sh = 1; sh < 64; sh <<= 1) s += __shfl_xor(s, sh);
    if (lane == 0) sq[row] = s;
}

// ---------------------------------------------------------------------------
// Kernel 2: triangular fused X.X^T GEMM + dist + masked exp reductions.
// Only bi >= bj tiles run (dist symmetric). Off-diagonal blocks emit BOTH
// column partials (slot bi, cols j0..) and row partials (slot bj, cols i0..).
// Epilogue is register-lean: (tm,r)-major traversal, row sums live in 3
// scalars (immediate shuffle-reduce + LDS write), col sums in 12 registers.
// Round-3 lesson: big live arrays pushed VGPR+AGPR > 256 -> 1 block/CU.
// ---------------------------------------------------------------------------
__global__ __launch_bounds__(256, 2) void gemm_fused(const ushort* __restrict__ xb,
                                                     const float* __restrict__ sq,
                                                     float* __restrict__ colPart) {
    __shared__ ushort smem[2 * BM * BK];   // 16 KB

    // triangular decode: blockIdx.x -> (bi, bj), bi >= bj
    int kblk = blockIdx.x;
    int bi = (int)((sqrtf(8.0f * kblk + 1.0f) - 1.0f) * 0.5f);
    if ((bi + 1) * (bi + 2) / 2 <= kblk) bi++;
    if (bi * (bi + 1) / 2 > kblk) bi--;
    int bj = kblk - bi * (bi + 1) / 2;

    const int i0 = bi * BM, j0 = bj * BN;
    const int tid = threadIdx.x;
    const int lane = tid & 63, wave = tid >> 6;
    const int wm = wave >> 1, wn = wave & 1;        // 2x2 waves over 128x128
    const int quad = lane >> 4, c16 = lane & 15;

    // staging coords: k-major within 16-row groups -> fragment reads are
    // base + lane*16 (conflict-free, m134 pattern)
    int s_half[4], s_row[4], s_kc[4];
    #pragma unroll
    for (int it = 0; it < 4; ++it) {
        int chunk = it * 256 + tid;          // 1024 chunks of 16B
        int half = chunk >> 9;               // 0 = A, 1 = B (wave-uniform)
        int c = chunk & 511;
        int g = c >> 6, p = c & 63;
        s_half[it] = half;
        s_kc[it] = p >> 4;
        s_row[it] = g * 16 + (p & 15);
    }

    floatx4 acc[4][4];
    #pragma unroll
    for (int a = 0; a < 4; ++a)
        #pragma unroll
        for (int b = 0; b < 4; ++b) acc[a][b] = (floatx4){0.f, 0.f, 0.f, 0.f};

    for (int kt = 0; kt < D; kt += BK) {
        #pragma unroll
        for (int it = 0; it < 4; ++it) {
            int grow = (s_half[it] ? j0 : i0) + s_row[it];
            const ushort* gp = xb + (size_t)grow * D + kt + s_kc[it] * 8;
            ushort* lp = smem + (it * 256 + tid) * 8;
            __builtin_amdgcn_global_load_lds(
                (const __attribute__((address_space(1))) void*)gp,
                (__attribute__((address_space(3))) void*)lp, 16, 0, 0);
        }
        __syncthreads();

        bf16x8 afrag[4], bfrag[4];
        #pragma unroll
        for (int t = 0; t < 4; ++t) {
            afrag[t] = *(const bf16x8*)(smem + (wm * 4 + t) * 512 + lane * 8);
            bfrag[t] = *(const bf16x8*)(smem + 4096 + (wn * 4 + t) * 512 + lane * 8);
        }
        #pragma unroll
        for (int tm = 0; tm < 4; ++tm)
            #pragma unroll
            for (int tn = 0; tn < 4; ++tn)
                acc[tm][tn] = __builtin_amdgcn_mfma_f32_16x16x32_bf16(
                    afrag[tm], bfrag[tn], acc[tm][tn], 0, 0, 0);
        __syncthreads();
    }

    // ---- epilogue ----
    // C/D layout: col = c16, row = quad*4 + r   [measured m89/m91]
    float sqj[4];
    #pragma unroll
    for (int tn = 0; tn < 4; ++tn)
        sqj[tn] = sq[j0 + wn * 64 + tn * 16 + c16];
    float sqi[4][4];
    #pragma unroll
    for (int tm = 0; tm < 4; ++tm)
        #pragma unroll
        for (int r = 0; r < 4; ++r)
            sqi[tm][r] = sq[i0 + wm * 64 + tm * 16 + quad * 4 + r];

    float* colBuf = (float*)smem;
    const bool diag = (bi == bj);          // same-class pairs only here (8|128)

    if (!diag) {
        float* rowBuf = colBuf + 768;      // colBuf [2][128][3], rowBuf [2][128][3]
        float cna[4] = {0.f, 0.f, 0.f, 0.f};
        float cnb[4] = {0.f, 0.f, 0.f, 0.f};
        float cnd[4] = {0.f, 0.f, 0.f, 0.f};
        #pragma unroll
        for (int tm = 0; tm < 4; ++tm) {
            #pragma unroll
            for (int r = 0; r < 4; ++r) {
                float rna = 0.f, rnb = 0.f, rnd = 0.f;
                #pragma unroll
                for (int tn = 0; tn < 4; ++tn) {
                    float dot = acc[tm][tn][r];
                    float dsq = sqi[tm][r] + sqj[tn] - 2.0f * dot;
                    float dist = sqrtf(fmaxf(dsq, 1e-12f));
                    float t = __expf(20.0f * (1.1f - dist));   // exp(BETA(1.1-d))
                    float t2 = t * t;                           // e^4*exp(40(1-d))
                    cna[tn] += t2; cnb[tn] += t; cnd[tn] += dist;
                    rna += t2;     rnb += t;     rnd += dist;
                }
                // row sums: reduce over the 16 c16 lanes, write, drop registers
                #pragma unroll
                for (int s = 1; s < 16; s <<= 1) {
                    rna += __shfl_xor(rna, s);
                    rnb += __shfl_xor(rnb, s);
                    rnd += __shfl_xor(rnd, s);
                }
                if (c16 == 0) {
                    int rb = wn * 384 + (wm * 64 + tm * 16 + quad * 4 + r) * 3;
                    rowBuf[rb + 0] = rna; rowBuf[rb + 1] = rnb; rowBuf[rb + 2] = rnd;
                }
            }
        }
        // col sums: reduce over quads
        #pragma unroll
        for (int tn = 0; tn < 4; ++tn) {
            #pragma unroll
            for (int s = 16; s < 64; s <<= 1) {
                cna[tn] += __shfl_xor(cna[tn], s);
                cnb[tn] += __shfl_xor(cnb[tn], s);
                cnd[tn] += __shfl_xor(cnd[tn], s);
            }
            if (quad == 0) {
                int cb = wm * 384 + (wn * 64 + tn * 16 + c16) * 3;
                colBuf[cb + 0] = cna[tn]; colBuf[cb + 1] = cnb[tn]; colBuf[cb + 2] = cnd[tn];
            }
        }
        __syncthreads();
        // stores: threads 0..127 -> col partials, 128..255 -> row partials
        if (tid < 128) {
            int j = tid;
            float na = colBuf[j * 3 + 0] + colBuf[384 + j * 3 + 0];
            float nb = colBuf[j * 3 + 1] + colBuf[384 + j * 3 + 1];
            float nd = colBuf[j * 3 + 2] + colBuf[384 + j * 3 + 2];
            float* dst = colPart + ((size_t)bi * N + j0 + j) * 6;
            dst[0] = 0.f; dst[1] = na; dst[2] = 0.f;
            dst[3] = nb; dst[4] = 0.f; dst[5] = nd;
        } else {
            int j = tid - 128;
            float na = rowBuf[j * 3 + 0] + rowBuf[384 + j * 3 + 0];
            float nb = rowBuf[j * 3 + 1] + rowBuf[384 + j * 3 + 1];
            float nd = rowBuf[j * 3 + 2] + rowBuf[384 + j * 3 + 2];
            float* dst = colPart + ((size_t)bj * N + i0 + j) * 6;
            dst[0] = 0.f; dst[1] = na; dst[2] = 0.f;
            dst[3] = nb; dst[4] = 0.f; dst[5] = nd;
        }
    } else {
        // diagonal tile: pos/neg masks live here; col sums only (symmetry)
        float cpa[4] = {0.f, 0.f, 0.f, 0.f};
        float cna[4] = {0.f, 0.f, 0.f, 0.f};
        float cpb[4] = {0.f, 0.f, 0.f, 0.f};
        float cnb[4] = {0.f, 0.f, 0.f, 0.f};
        float cpd[4] = {0.f, 0.f, 0.f, 0.f};
        float cnd[4] = {0.f, 0.f, 0.f, 0.f};
        #pragma unroll
        for (int tm = 0; tm < 4; ++tm) {
            #pragma unroll
            for (int r = 0; r < 4; ++r) {
                const int gi = i0 + wm * 64 + tm * 16 + quad * 4 + r;
                #pragma unroll
                for (int tn = 0; tn < 4; ++tn) {
                    const int gj = j0 + wn * 64 + tn * 16 + c16;
                    float dot = acc[tm][tn][r];
                    float dsq = sqi[tm][r] + sqj[tn] - 2.0f * dot;
                    float dist = sqrtf(fmaxf(dsq, 1e-12f));
                    float t = __expf(20.0f * (1.1f - dist));
                    float t2 = t * t;
                    bool same = (gi >> 3) == (gj >> 3);
                    float sp = (same && gi != gj) ? 1.f : 0.f;
                    float sn = same ? 0.f : 1.f;
                    float pe = __expf(20.0f * (dist - 0.8f));
                    cpa[tn] += sp * t2;   cna[tn] += sn * t2;
                    cpb[tn] += sp * pe;   cnb[tn] += sn * t;
                    cpd[tn] += sp * dist; cnd[tn] += sn * dist;
                }
            }
        }
        #pragma unroll
        for (int tn = 0; tn < 4; ++tn) {
            #pragma unroll
            for (int s = 16; s < 64; s <<= 1) {
                cpa[tn] += __shfl_xor(cpa[tn], s); cna[tn] += __shfl_xor(cna[tn], s);
                cpb[tn] += __shfl_xor(cpb[tn], s); cnb[tn] += __shfl_xor(cnb[tn], s);
                cpd[tn] += __shfl_xor(cpd[tn], s); cnd[tn] += __shfl_xor(cnd[tn], s);
            }
            if (quad == 0) {
                int cb = (wm * 128 + wn * 64 + tn * 16 + c16) * 6;
                colBuf[cb + 0] = cpa[tn]; colBuf[cb + 1] = cna[tn];
                colBuf[cb + 2] = cpb[tn]; colBuf[cb + 3] = cnb[tn];
                colBuf[cb + 4] = cpd[tn]; colBuf[cb + 5] = cnd[tn];
            }
        }
        __syncthreads();
        if (tid < 128) {
            int j = tid;
            float* dst = colPart + ((size_t)bi * N + j0 + j) * 6;
            #pragma unroll
            for (int c = 0; c < 6; ++c)
                dst[c] = colBuf[j * 6 + c] + colBuf[(128 + j) * 6 + c];
        }
    }
}

// ---------------------------------------------------------------------------
// Kernel 3: reduce the 32 per-block partial slots -> per-row loss pieces
// ---------------------------------------------------------------------------
__global__ __launch_bounds__(256) void reduce_rows(const float* __restrict__ colPart,
                                                   float* __restrict__ rowOut) {
    int j = blockIdx.x * 256 + threadIdx.x;     // 4096 threads total
    float pa = 0.f, na = 0.f, pb = 0.f, nb = 0.f, pd = 0.f, nd = 0.f;
    for (int s = 0; s < NSLOT; ++s) {
        const float* p = colPart + (size_t)s * N * 6 + (size_t)j * 6;
        pa += p[0]; na += p[1]; pb += p[2];
        nb += p[3]; pd += p[4]; nd += p[5];
    }
    // pa/na both carry the same e^4 factor vs exp(40(1-d)) -> cancels in a_lr
    float a_lr = 1.0f - pa / (pa + na);
    rowOut[j * 3 + 0] = a_lr * (logf(pb) + logf(nb));
    rowOut[j * 3 + 1] = pd;
    rowOut[j * 3 + 2] = nd;
}

// ---------------------------------------------------------------------------
// Kernel 4: global means
// ---------------------------------------------------------------------------
__global__ __launch_bounds__(256) void finalize_kernel(const float* __restrict__ rowOut,
                                                       float* __restrict__ out) {
    int tid = threadIdx.x;
    float L = 0.f, P = 0.f, G = 0.f;
    for (int i = tid; i < N; i += 256) {
        L += rowOut[i * 3 + 0];
        P += rowOut[i * 3 + 1];
        G += rowOut[i * 3 + 2];
    }
    #pragma unroll
    for (int s = 1; s < 64; s <<= 1) {
        L += __shfl_xor(L, s);
        P += __shfl_xor(P, s);
        G += __shfl_xor(G, s);
    }
    __shared__ float r0[4], r1[4], r2[4];
    int lane = tid & 63, w = tid >> 6;
    if (lane == 0) { r0[w] = L; r1[w] = P; r2[w] = G; }
    __syncthreads();
    if (tid == 0) {
        float Ls = r0[0] + r0[1] + r0[2] + r0[3];
        float Ps = r1[0] + r1[1] + r1[2] + r1[3];
        float Gs = r2[0] + r2[1] + r2[2] + r2[3];
        out[0] = Ls / (float)N;
        out[1] = 0.0f;                                   // accuracy never incremented
        out[2] = Ps / ((float)N * 7.0f);                 // pos pairs per row = 7
        out[3] = Gs / ((float)N * (float)(N - 8));       // neg pairs per row = 4088
    }
}

// ---------------------------------------------------------------------------
extern "C" void kernel_launch(void* const* d_in, const int* in_sizes, int n_in,
                              void* d_out, int out_size, void* d_ws, size_t ws_size,
                              hipStream_t stream) {
    const float* x = (const float*)d_in[0];
    float* out = (float*)d_out;
    char* ws = (char*)d_ws;

    ushort* xb      = (ushort*)ws;                                   // 8 MB bf16 matrix
    float*  sq      = (float*)(ws + (size_t)N * D * 2);              // 16 KB row norms
    float*  colPart = (float*)(ws + (size_t)N * D * 2 + N * 4);      // 3 MB partials
    float*  rowOut  = (float*)(ws + (size_t)N * D * 2 + N * 4
                               + (size_t)NSLOT * N * 6 * 4);         // 48 KB

    prep_kernel<<<N / 4, 256, 0, stream>>>(x, xb, sq);

    gemm_fused<<<NTRI, 256, 0, stream>>>(xb, sq, colPart);

    reduce_rows<<<N / 256, 256, 0, stream>>>(colPart, rowOut);
    finalize_kernel<<<1, 256, 0, stream>>>(rowOut, out);
}

// Round 5
// 140.723 us; speedup vs baseline: 1.1160x; 1.1160x over previous
//
#include <hip/hip_runtime.h>

#define N 4096
#define D 1024
#define BM 128
#define BN 128
#define BK 32
#define NSLOT 32   // N / BM partial-slots per column

typedef __bf16 bf16x8 __attribute__((ext_vector_type(8)));
typedef float floatx4 __attribute__((ext_vector_type(4)));

__device__ __forceinline__ ushort f2bf(float f) {
    union { float f; uint32_t u; } c; c.f = f;
    uint32_t u = c.u;
    uint32_t r = u + 0x7FFFu + ((u >> 16) & 1u);
    return (ushort)(r >> 16);
}

// ---------------------------------------------------------------------------
// Kernel 1: fp32 -> bf16 + per-row squared norm. One wave per row, no LDS.
// Thread (0,0) also zero-inits d_out for the downstream atomic finalize.
// ---------------------------------------------------------------------------
__global__ __launch_bounds__(256) void prep_kernel(const float* __restrict__ x,
                                                   ushort* __restrict__ xb,
                                                   float* __restrict__ sq,
                                                   float* __restrict__ out) {
    if (blockIdx.x == 0 && threadIdx.x == 0) {
        out[0] = 0.f; out[1] = 0.f; out[2] = 0.f; out[3] = 0.f;
    }
    int row = blockIdx.x * 4 + (threadIdx.x >> 6);
    int lane = threadIdx.x & 63;
    const float4* xr = (const float4*)(x + (size_t)row * D);
    ushort4* br = (ushort4*)(xb + (size_t)row * D);
    float s = 0.f;
    #pragma unroll
    for (int j = 0; j < 4; ++j) {
        float4 v = xr[j * 64 + lane];
        s += v.x * v.x + v.y * v.y + v.z * v.z + v.w * v.w;
        br[j * 64 + lane] = make_ushort4(f2bf(v.x), f2bf(v.y), f2bf(v.z), f2bf(v.w));
    }
    #pragma unroll
    for (int sh = 1; sh < 64; sh <<= 1) s += __shfl_xor(s, sh);
    if (lane == 0) sq[row] = s;
}

// ---------------------------------------------------------------------------
// Kernel 2: full-grid fused X.X^T GEMM (bf16 MFMA) + dist + masked exp
// COLUMN-reductions (round-2 structure, VGPR~60, 2+ blocks/CU) with the
// conflict-free LDS layout from round 3 (k-major within 16-row groups ->
// fragment ds_read_b128 at base + lane*16; measured 4.19M -> 0 conflicts).
// Round-3/4 lesson: triangle + dual-direction epilogue costs more in
// occupancy/spills than the 2x MFMA saving is worth. Keep it simple.
// ---------------------------------------------------------------------------
__global__ __launch_bounds__(256, 2) void gemm_fused(const ushort* __restrict__ xb,
                                                     const float* __restrict__ sq,
                                                     float* __restrict__ colPart) {
    __shared__ ushort smem[2 * BM * BK];   // 16 KB

    const int bi = blockIdx.y, bj = blockIdx.x;
    const int i0 = bi * BM, j0 = bj * BN;
    const int tid = threadIdx.x;
    const int lane = tid & 63, wave = tid >> 6;
    const int wm = wave >> 1, wn = wave & 1;        // 2x2 waves over 128x128
    const int quad = lane >> 4, c16 = lane & 15;

    // staging: chunk -> (half, group g, k-col kc, row r); LDS pos = chunk*16B
    // within a 1KB group the 64 chunks are (kc, r) k-major -> fragment reads
    // become group*1024B + lane*16B (conflict-free)
    int goff[4];
    #pragma unroll
    for (int it = 0; it < 4; ++it) {
        int chunk = it * 256 + tid;          // 1024 chunks of 16B
        int half = chunk >> 9;               // 0 = A, 1 = B (wave-uniform)
        int c = chunk & 511;
        int g = c >> 6, p = c & 63;
        int kc = p >> 4, r = p & 15;
        int grow = (half ? j0 : i0) + g * 16 + r;
        goff[it] = grow * D + kc * 8;        // element offset; += kt per iter
    }

    floatx4 acc[4][4];
    #pragma unroll
    for (int a = 0; a < 4; ++a)
        #pragma unroll
        for (int b = 0; b < 4; ++b) acc[a][b] = (floatx4){0.f, 0.f, 0.f, 0.f};

    for (int kt = 0; kt < D; kt += BK) {
        #pragma unroll
        for (int it = 0; it < 4; ++it) {
            const ushort* gp = xb + goff[it] + kt;
            ushort* lp = smem + (it * 256 + tid) * 8;   // lane-contiguous 16B
            __builtin_amdgcn_global_load_lds(
                (const __attribute__((address_space(1))) void*)gp,
                (__attribute__((address_space(3))) void*)lp, 16, 0, 0);
        }
        __syncthreads();   // drains vmcnt -> LDS tiles ready

        bf16x8 afrag[4], bfrag[4];
        #pragma unroll
        for (int t = 0; t < 4; ++t) {
            afrag[t] = *(const bf16x8*)(smem + (wm * 4 + t) * 512 + lane * 8);
            bfrag[t] = *(const bf16x8*)(smem + 4096 + (wn * 4 + t) * 512 + lane * 8);
        }
        #pragma unroll
        for (int tm = 0; tm < 4; ++tm)
            #pragma unroll
            for (int tn = 0; tn < 4; ++tn)
                acc[tm][tn] = __builtin_amdgcn_mfma_f32_16x16x32_bf16(
                    afrag[tm], bfrag[tn], acc[tm][tn], 0, 0, 0);
        __syncthreads();   // protect LDS before next stage overwrites
    }

    // ---- epilogue: column partial sums (round-2 structure) ----
    // C/D layout: col = c16, row = quad*4 + r   [measured m89/m91]
    float sqi[4][4];
    #pragma unroll
    for (int tm = 0; tm < 4; ++tm)
        #pragma unroll
        for (int r = 0; r < 4; ++r)
            sqi[tm][r] = sq[i0 + wm * 64 + tm * 16 + quad * 4 + r];
    float sqj[4];
    #pragma unroll
    for (int tn = 0; tn < 4; ++tn)
        sqj[tn] = sq[j0 + wn * 64 + tn * 16 + c16];

    float cpa[4], cna[4], cpb[4], cnb[4], cpd[4], cnd[4];
    const bool diag = (bi == bj);   // same-class pairs only occur here (8 | 128)

    #pragma unroll
    for (int tn = 0; tn < 4; ++tn) {
        float pa = 0.f, na = 0.f, pb = 0.f, nb = 0.f, pd = 0.f, nd = 0.f;
        if (!diag) {
            // pure negatives: branch-free
            #pragma unroll
            for (int tm = 0; tm < 4; ++tm)
                #pragma unroll
                for (int r = 0; r < 4; ++r) {
                    float dot = acc[tm][tn][r];
                    float dsq = sqi[tm][r] + sqj[tn] - 2.0f * dot;
                    float dist = sqrtf(fmaxf(dsq, 1e-12f));
                    float t = __expf(20.0f * (1.1f - dist));   // exp(BETA(1.1-d))
                    na = fmaf(t, t, na);                        // e^4 * exp(40(1-d))
                    nb += t;
                    nd += dist;
                }
        } else {
            const int gj = j0 + wn * 64 + tn * 16 + c16;
            const int gjc = gj >> 3;
            #pragma unroll
            for (int tm = 0; tm < 4; ++tm)
                #pragma unroll
                for (int r = 0; r < 4; ++r) {
                    const int gi = i0 + wm * 64 + tm * 16 + quad * 4 + r;
                    float dot = acc[tm][tn][r];
                    float dsq = sqi[tm][r] + sqj[tn] - 2.0f * dot;
                    float dist = sqrtf(fmaxf(dsq, 1e-12f));
                    float t = __expf(20.0f * (1.1f - dist));
                    bool same = (gi >> 3) == gjc;
                    if (same) {
                        if (gi != gj) {
                            pa = fmaf(t, t, pa);
                            pb += __expf(20.0f * (dist - 0.8f));
                            pd += dist;
                        }
                    } else {
                        na = fmaf(t, t, na);
                        nb += t;
                        nd += dist;
                    }
                }
        }
        cpa[tn] = pa; cna[tn] = na; cpb[tn] = pb;
        cnb[tn] = nb; cpd[tn] = pd; cnd[tn] = nd;
    }

    // reduce the 4 quads (each column's 64 rows): lanes ^16, ^32 only
    #pragma unroll
    for (int tn = 0; tn < 4; ++tn) {
        #pragma unroll
        for (int s = 16; s < 64; s <<= 1) {
            cna[tn] += __shfl_xor(cna[tn], s);
            cnb[tn] += __shfl_xor(cnb[tn], s);
            cnd[tn] += __shfl_xor(cnd[tn], s);
        }
        if (diag) {
            #pragma unroll
            for (int s = 16; s < 64; s <<= 1) {
                cpa[tn] += __shfl_xor(cpa[tn], s);
                cpb[tn] += __shfl_xor(cpb[tn], s);
                cpd[tn] += __shfl_xor(cpd[tn], s);
            }
        }
    }

    // combine the two wm halves via LDS (smem is free after last barrier)
    float* colBuf = (float*)smem;   // [2][128][6] floats = 6 KB
    #pragma unroll
    for (int tn = 0; tn < 4; ++tn) {
        // all 4 quads hold identical reduced values; same-addr same-value writes
        int cb = (wm * 128 + wn * 64 + tn * 16 + c16) * 6;
        colBuf[cb + 0] = cpa[tn]; colBuf[cb + 1] = cna[tn];
        colBuf[cb + 2] = cpb[tn]; colBuf[cb + 3] = cnb[tn];
        colBuf[cb + 4] = cpd[tn]; colBuf[cb + 5] = cnd[tn];
    }
    __syncthreads();

    // atomic-free partial store: contiguous 3 KB per block
    float* dst = colPart + (size_t)bi * N * 6 + (size_t)j0 * 6;
    #pragma unroll
    for (int it = 0; it < 3; ++it) {
        int idx = it * 256 + tid;               // 0..767
        dst[idx] = colBuf[idx] + colBuf[768 + idx];
    }
}

// ---------------------------------------------------------------------------
// Kernel 3: reduce the 32 per-block partial slots -> per-row loss pieces,
// then block-reduce and atomically accumulate the 3 global means into out.
// (out zero-initialized by prep_kernel; stream serialization guarantees order)
// ---------------------------------------------------------------------------
__global__ __launch_bounds__(256) void reduce_finalize(const float* __restrict__ colPart,
                                                       float* __restrict__ out) {
    int j = blockIdx.x * 256 + threadIdx.x;     // 4096 threads total
    float pa = 0.f, na = 0.f, pb = 0.f, nb = 0.f, pd = 0.f, nd = 0.f;
    for (int s = 0; s < NSLOT; ++s) {
        const float* p = colPart + (size_t)s * N * 6 + (size_t)j * 6;
        pa += p[0]; na += p[1]; pb += p[2];
        nb += p[3]; pd += p[4]; nd += p[5];
    }
    // pa/na both carry the same e^4 factor vs exp(40(1-d)) -> cancels in a_lr
    float a_lr = 1.0f - pa / (pa + na);
    float L = a_lr * (logf(pb) + logf(nb));

    #pragma unroll
    for (int s = 1; s < 64; s <<= 1) {
        L  += __shfl_xor(L, s);
        pd += __shfl_xor(pd, s);
        nd += __shfl_xor(nd, s);
    }
    __shared__ float r0[4], r1[4], r2[4];
    int lane = threadIdx.x & 63, w = threadIdx.x >> 6;
    if (lane == 0) { r0[w] = L; r1[w] = pd; r2[w] = nd; }
    __syncthreads();
    if (threadIdx.x == 0) {
        float Ls = r0[0] + r0[1] + r0[2] + r0[3];
        float Ps = r1[0] + r1[1] + r1[2] + r1[3];
        float Gs = r2[0] + r2[1] + r2[2] + r2[3];
        atomicAdd(out + 0, Ls / (float)N);
        atomicAdd(out + 2, Ps / ((float)N * 7.0f));              // 7 pos pairs/row
        atomicAdd(out + 3, Gs / ((float)N * (float)(N - 8)));    // 4088 neg/row
        // out[1] (accuracy) stays 0 from prep's init
    }
}

// ---------------------------------------------------------------------------
extern "C" void kernel_launch(void* const* d_in, const int* in_sizes, int n_in,
                              void* d_out, int out_size, void* d_ws, size_t ws_size,
                              hipStream_t stream) {
    const float* x = (const float*)d_in[0];
    float* out = (float*)d_out;
    char* ws = (char*)d_ws;

    ushort* xb      = (ushort*)ws;                                   // 8 MB bf16 matrix
    float*  sq      = (float*)(ws + (size_t)N * D * 2);              // 16 KB row norms
    float*  colPart = (float*)(ws + (size_t)N * D * 2 + N * 4);      // 3 MB partials

    prep_kernel<<<N / 4, 256, 0, stream>>>(x, xb, sq, out);

    dim3 grid(N / BN, N / BM);
    gemm_fused<<<grid, 256, 0, stream>>>(xb, sq, colPart);

    reduce_finalize<<<N / 256, 256, 0, stream>>>(colPart, out);
}

// Round 6
// 115.114 us; speedup vs baseline: 1.3643x; 1.2225x over previous
//
#include <hip/hip_runtime.h>

#define N 4096
#define D 1024
#define BM 128
#define BN 128
#define BK 32
#define NSLOT 32   // N / BM partial-slots per column

typedef __bf16 bf16x8 __attribute__((ext_vector_type(8)));
typedef float floatx4 __attribute__((ext_vector_type(4)));

__device__ __forceinline__ ushort f2bf(float f) {
    union { float f; uint32_t u; } c; c.f = f;
    uint32_t u = c.u;
    uint32_t r = u + 0x7FFFu + ((u >> 16) & 1u);
    return (ushort)(r >> 16);
}

// ---------------------------------------------------------------------------
// Kernel 1: fp32 -> bf16 + per-row squared norm. One wave per row, no LDS.
// Thread (0,0) also zero-inits d_out for the downstream atomic finalize.
// ---------------------------------------------------------------------------
__global__ __launch_bounds__(256) void prep_kernel(const float* __restrict__ x,
                                                   ushort* __restrict__ xb,
                                                   float* __restrict__ sq,
                                                   float* __restrict__ out) {
    if (blockIdx.x == 0 && threadIdx.x == 0) {
        out[0] = 0.f; out[1] = 0.f; out[2] = 0.f; out[3] = 0.f;
    }
    int row = blockIdx.x * 4 + (threadIdx.x >> 6);
    int lane = threadIdx.x & 63;
    const float4* xr = (const float4*)(x + (size_t)row * D);
    ushort4* br = (ushort4*)(xb + (size_t)row * D);
    float s = 0.f;
    #pragma unroll
    for (int j = 0; j < 4; ++j) {
        float4 v = xr[j * 64 + lane];
        s += v.x * v.x + v.y * v.y + v.z * v.z + v.w * v.w;
        br[j * 64 + lane] = make_ushort4(f2bf(v.x), f2bf(v.y), f2bf(v.z), f2bf(v.w));
    }
    #pragma unroll
    for (int sh = 1; sh < 64; sh <<= 1) s += __shfl_xor(s, sh);
    if (lane == 0) sq[row] = s;
}

// ---------------------------------------------------------------------------
// Kernel 2: full-grid fused X.X^T GEMM (bf16 MFMA) + dist + masked exp
// COLUMN-reductions. LDS layout is kc-XOR-swizzled so that BOTH:
//  (a) global staging quarter-waves cover 4 full 64B lines (round-2 coalescing;
//      round-5's k-major layout scattered 16 lines/quarter -> 26us regression)
//  (b) fragment ds_read_b128 slots hit all 8 bank residues 2x (conflict-free;
//      round-2's row-major layout was 2-residue -> 4.19M conflict cycles)
// Slot s in a 1KB 16-row group holds (row = s>>2, kc = ((s&3)-((s>>3)&3))&3);
// content (r,kc) lives at slot r*4 + ((kc + (r>>1))&3).
// ---------------------------------------------------------------------------
__global__ __launch_bounds__(256, 2) void gemm_fused(const ushort* __restrict__ xb,
                                                     const float* __restrict__ sq,
                                                     float* __restrict__ colPart) {
    __shared__ ushort smem[2 * BM * BK];   // 16 KB

    const int bi = blockIdx.y, bj = blockIdx.x;
    const int i0 = bi * BM, j0 = bj * BN;
    const int tid = threadIdx.x;
    const int lane = tid & 63, wave = tid >> 6;
    const int wm = wave >> 1, wn = wave & 1;        // 2x2 waves over 128x128
    const int quad = lane >> 4, c16 = lane & 15;

    // staging source offsets (slot = lane position, content per swizzle above)
    int goff[4];
    #pragma unroll
    for (int it = 0; it < 4; ++it) {
        int chunk = it * 256 + tid;          // 1024 chunks of 16B
        int half = chunk >> 9;               // 0 = A, 1 = B (wave-uniform)
        int c = chunk & 511;
        int g = c >> 6, s = c & 63;
        int r = s >> 2;
        int kc = ((s & 3) - ((s >> 3) & 3)) & 3;
        int grow = (half ? j0 : i0) + g * 16 + r;
        goff[it] = grow * D + kc * 8;        // element offset; += kt per iter
    }
    // fragment slot within a group for this lane (ushort offset = slot*8)
    const int fslot = (c16 << 2) | ((quad + (c16 >> 1)) & 3);

    floatx4 acc[4][4];
    #pragma unroll
    for (int a = 0; a < 4; ++a)
        #pragma unroll
        for (int b = 0; b < 4; ++b) acc[a][b] = (floatx4){0.f, 0.f, 0.f, 0.f};

    for (int kt = 0; kt < D; kt += BK) {
        #pragma unroll
        for (int it = 0; it < 4; ++it) {
            const ushort* gp = xb + goff[it] + kt;
            ushort* lp = smem + (it * 256 + tid) * 8;   // lane-contiguous 16B
            __builtin_amdgcn_global_load_lds(
                (const __attribute__((address_space(1))) void*)gp,
                (__attribute__((address_space(3))) void*)lp, 16, 0, 0);
        }
        __syncthreads();   // drains vmcnt -> LDS tiles ready

        bf16x8 afrag[4], bfrag[4];
        #pragma unroll
        for (int t = 0; t < 4; ++t) {
            afrag[t] = *(const bf16x8*)(smem + (wm * 4 + t) * 512 + fslot * 8);
            bfrag[t] = *(const bf16x8*)(smem + 4096 + (wn * 4 + t) * 512 + fslot * 8);
        }
        #pragma unroll
        for (int tm = 0; tm < 4; ++tm)
            #pragma unroll
            for (int tn = 0; tn < 4; ++tn)
                acc[tm][tn] = __builtin_amdgcn_mfma_f32_16x16x32_bf16(
                    afrag[tm], bfrag[tn], acc[tm][tn], 0, 0, 0);
        __syncthreads();   // protect LDS before next stage overwrites
    }

    // ---- epilogue: column partial sums ----
    // C/D layout: col = c16, row = quad*4 + r   [measured m89/m91]
    float sqi[4][4];
    #pragma unroll
    for (int tm = 0; tm < 4; ++tm)
        #pragma unroll
        for (int r = 0; r < 4; ++r)
            sqi[tm][r] = sq[i0 + wm * 64 + tm * 16 + quad * 4 + r];
    float sqj[4];
    #pragma unroll
    for (int tn = 0; tn < 4; ++tn)
        sqj[tn] = sq[j0 + wn * 64 + tn * 16 + c16];

    float cpa[4], cna[4], cpb[4], cnb[4], cpd[4], cnd[4];
    const bool diag = (bi == bj);   // same-class pairs only occur here (8 | 128)

    #pragma unroll
    for (int tn = 0; tn < 4; ++tn) {
        float pa = 0.f, na = 0.f, pb = 0.f, nb = 0.f, pd = 0.f, nd = 0.f;
        if (!diag) {
            // pure negatives: branch-free
            #pragma unroll
            for (int tm = 0; tm < 4; ++tm)
                #pragma unroll
                for (int r = 0; r < 4; ++r) {
                    float dot = acc[tm][tn][r];
                    float dsq = sqi[tm][r] + sqj[tn] - 2.0f * dot;
                    float dist = sqrtf(fmaxf(dsq, 1e-12f));
                    float t = __expf(20.0f * (1.1f - dist));   // exp(BETA(1.1-d))
                    na = fmaf(t, t, na);                        // e^4 * exp(40(1-d))
                    nb += t;
                    nd += dist;
                }
        } else {
            const int gj = j0 + wn * 64 + tn * 16 + c16;
            const int gjc = gj >> 3;
            #pragma unroll
            for (int tm = 0; tm < 4; ++tm)
                #pragma unroll
                for (int r = 0; r < 4; ++r) {
                    const int gi = i0 + wm * 64 + tm * 16 + quad * 4 + r;
                    float dot = acc[tm][tn][r];
                    float dsq = sqi[tm][r] + sqj[tn] - 2.0f * dot;
                    float dist = sqrtf(fmaxf(dsq, 1e-12f));
                    float t = __expf(20.0f * (1.1f - dist));
                    bool same = (gi >> 3) == gjc;
                    if (same) {
                        if (gi != gj) {
                            pa = fmaf(t, t, pa);
                            pb += __expf(20.0f * (dist - 0.8f));
                            pd += dist;
                        }
                    } else {
                        na = fmaf(t, t, na);
                        nb += t;
                        nd += dist;
                    }
                }
        }
        cpa[tn] = pa; cna[tn] = na; cpb[tn] = pb;
        cnb[tn] = nb; cpd[tn] = pd; cnd[tn] = nd;
    }

    // reduce the 4 quads (each column's 64 rows): lanes ^16, ^32 only
    #pragma unroll
    for (int tn = 0; tn < 4; ++tn) {
        #pragma unroll
        for (int s = 16; s < 64; s <<= 1) {
            cna[tn] += __shfl_xor(cna[tn], s);
            cnb[tn] += __shfl_xor(cnb[tn], s);
            cnd[tn] += __shfl_xor(cnd[tn], s);
        }
        if (diag) {
            #pragma unroll
            for (int s = 16; s < 64; s <<= 1) {
                cpa[tn] += __shfl_xor(cpa[tn], s);
                cpb[tn] += __shfl_xor(cpb[tn], s);
                cpd[tn] += __shfl_xor(cpd[tn], s);
            }
        }
    }

    // combine the two wm halves via LDS (smem is free after last barrier)
    float* colBuf = (float*)smem;   // [2][128][6] floats = 6 KB
    #pragma unroll
    for (int tn = 0; tn < 4; ++tn) {
        // all 4 quads hold identical reduced values; same-addr same-value writes
        int cb = (wm * 128 + wn * 64 + tn * 16 + c16) * 6;
        colBuf[cb + 0] = cpa[tn]; colBuf[cb + 1] = cna[tn];
        colBuf[cb + 2] = cpb[tn]; colBuf[cb + 3] = cnb[tn];
        colBuf[cb + 4] = cpd[tn]; colBuf[cb + 5] = cnd[tn];
    }
    __syncthreads();

    // atomic-free partial store: contiguous 3 KB per block
    float* dst = colPart + (size_t)bi * N * 6 + (size_t)j0 * 6;
    #pragma unroll
    for (int it = 0; it < 3; ++it) {
        int idx = it * 256 + tid;               // 0..767
        dst[idx] = colBuf[idx] + colBuf[768 + idx];
    }
}

// ---------------------------------------------------------------------------
// Kernel 3: reduce the 32 per-block partial slots -> per-row loss pieces,
// then block-reduce and atomically accumulate the 3 global means into out.
// (out zero-initialized by prep_kernel; stream serialization guarantees order)
// ---------------------------------------------------------------------------
__global__ __launch_bounds__(256) void reduce_finalize(const float* __restrict__ colPart,
                                                       float* __restrict__ out) {
    int j = blockIdx.x * 256 + threadIdx.x;     // 4096 threads total
    float pa = 0.f, na = 0.f, pb = 0.f, nb = 0.f, pd = 0.f, nd = 0.f;
    for (int s = 0; s < NSLOT; ++s) {
        const float* p = colPart + (size_t)s * N * 6 + (size_t)j * 6;
        pa += p[0]; na += p[1]; pb += p[2];
        nb += p[3]; pd += p[4]; nd += p[5];
    }
    // pa/na both carry the same e^4 factor vs exp(40(1-d)) -> cancels in a_lr
    float a_lr = 1.0f - pa / (pa + na);
    float L = a_lr * (logf(pb) + logf(nb));

    #pragma unroll
    for (int s = 1; s < 64; s <<= 1) {
        L  += __shfl_xor(L, s);
        pd += __shfl_xor(pd, s);
        nd += __shfl_xor(nd, s);
    }
    __shared__ float r0[4], r1[4], r2[4];
    int lane = threadIdx.x & 63, w = threadIdx.x >> 6;
    if (lane == 0) { r0[w] = L; r1[w] = pd; r2[w] = nd; }
    __syncthreads();
    if (threadIdx.x == 0) {
        float Ls = r0[0] + r0[1] + r0[2] + r0[3];
        float Ps = r1[0] + r1[1] + r1[2] + r1[3];
        float Gs = r2[0] + r2[1] + r2[2] + r2[3];
        atomicAdd(out + 0, Ls / (float)N);
        atomicAdd(out + 2, Ps / ((float)N * 7.0f));              // 7 pos pairs/row
        atomicAdd(out + 3, Gs / ((float)N * (float)(N - 8)));    // 4088 neg/row
        // out[1] (accuracy) stays 0 from prep's init
    }
}

// ---------------------------------------------------------------------------
extern "C" void kernel_launch(void* const* d_in, const int* in_sizes, int n_in,
                              void* d_out, int out_size, void* d_ws, size_t ws_size,
                              hipStream_t stream) {
    const float* x = (const float*)d_in[0];
    float* out = (float*)d_out;
    char* ws = (char*)d_ws;

    ushort* xb      = (ushort*)ws;                                   // 8 MB bf16 matrix
    float*  sq      = (float*)(ws + (size_t)N * D * 2);              // 16 KB row norms
    float*  colPart = (float*)(ws + (size_t)N * D * 2 + N * 4);      // 3 MB partials

    prep_kernel<<<N / 4, 256, 0, stream>>>(x, xb, sq, out);

    dim3 grid(N / BN, N / BM);
    gemm_fused<<<grid, 256, 0, stream>>>(xb, sq, colPart);

    reduce_finalize<<<N / 256, 256, 0, stream>>>(colPart, out);
}

// Round 7
// 108.765 us; speedup vs baseline: 1.4439x; 1.0584x over previous
//
#include <hip/hip_runtime.h>

#define N 4096
#define D 1024
#define BM 128
#define BN 128
#define BK 64
#define NSLOT 32   // N / BM partial-slots per column

typedef __bf16 bf16x8 __attribute__((ext_vector_type(8)));
typedef float floatx4 __attribute__((ext_vector_type(4)));

__device__ __forceinline__ ushort f2bf(float f) {
    union { float f; uint32_t u; } c; c.f = f;
    uint32_t u = c.u;
    uint32_t r = u + 0x7FFFu + ((u >> 16) & 1u);
    return (ushort)(r >> 16);
}

// ---------------------------------------------------------------------------
// Kernel 1: fp32 -> bf16 + per-row squared norm. One wave per row, no LDS.
// Thread (0,0) also zero-inits d_out for the downstream atomic finalize.
// ---------------------------------------------------------------------------
__global__ __launch_bounds__(256) void prep_kernel(const float* __restrict__ x,
                                                   ushort* __restrict__ xb,
                                                   float* __restrict__ sq,
                                                   float* __restrict__ out) {
    if (blockIdx.x == 0 && threadIdx.x == 0) {
        out[0] = 0.f; out[1] = 0.f; out[2] = 0.f; out[3] = 0.f;
    }
    int row = blockIdx.x * 4 + (threadIdx.x >> 6);
    int lane = threadIdx.x & 63;
    const float4* xr = (const float4*)(x + (size_t)row * D);
    ushort4* br = (ushort4*)(xb + (size_t)row * D);
    float s = 0.f;
    #pragma unroll
    for (int j = 0; j < 4; ++j) {
        float4 v = xr[j * 64 + lane];
        s += v.x * v.x + v.y * v.y + v.z * v.z + v.w * v.w;
        br[j * 64 + lane] = make_ushort4(f2bf(v.x), f2bf(v.y), f2bf(v.z), f2bf(v.w));
    }
    #pragma unroll
    for (int sh = 1; sh < 64; sh <<= 1) s += __shfl_xor(s, sh);
    if (lane == 0) sq[row] = s;
}

// ---------------------------------------------------------------------------
// Kernel 2: full-grid fused X.X^T GEMM (bf16 MFMA) + dist + masked exp
// COLUMN-reductions. BK=64: halves the per-K-loop barrier count (the
// structural vmcnt(0) drain before s_barrier is the m97-plateau stall);
// 32 KB LDS still allows 5 blocks/CU. LDS groups = 16 rows x 64 elems (2 KB),
// slot s in group holds (r = s>>3, kc = ((s&7)-(r>>1))&7):
//  (a) staging quarter-waves cover full 128B row segments (coalesced)
//  (b) fragment ds_read_b128 sweeps all 8 bank residues 2x (2-way = free)
// ---------------------------------------------------------------------------
__global__ __launch_bounds__(256, 2) void gemm_fused(const ushort* __restrict__ xb,
                                                     const float* __restrict__ sq,
                                                     float* __restrict__ colPart) {
    __shared__ ushort smem[2 * BM * BK];   // 32 KB

    const int bi = blockIdx.y, bj = blockIdx.x;
    const int i0 = bi * BM, j0 = bj * BN;
    const int tid = threadIdx.x;
    const int lane = tid & 63, wave = tid >> 6;
    const int wm = wave >> 1, wn = wave & 1;        // 2x2 waves over 128x128
    const int quad = lane >> 4, c16 = lane & 15;

    // staging source offsets (slot = lane position, content per swizzle above)
    int goff[8];
    #pragma unroll
    for (int it = 0; it < 8; ++it) {
        int chunk = it * 256 + tid;          // 2048 chunks of 16B
        int half = chunk >> 10;              // 0 = A, 1 = B (wave-uniform)
        int c = chunk & 1023;
        int g = c >> 7, p = c & 127;         // 8 groups of (16 rows x 8 kc)
        int r = p >> 3;
        int kc = ((p & 7) - (r >> 1)) & 7;
        int grow = (half ? j0 : i0) + g * 16 + r;
        goff[it] = grow * D + kc * 8;        // element offset; += kt per iter
    }

    floatx4 acc[4][4];
    #pragma unroll
    for (int a = 0; a < 4; ++a)
        #pragma unroll
        for (int b = 0; b < 4; ++b) acc[a][b] = (floatx4){0.f, 0.f, 0.f, 0.f};

    for (int kt = 0; kt < D; kt += BK) {
        #pragma unroll
        for (int it = 0; it < 8; ++it) {
            const ushort* gp = xb + goff[it] + kt;
            ushort* lp = smem + (it * 256 + tid) * 8;   // lane-contiguous 16B
            __builtin_amdgcn_global_load_lds(
                (const __attribute__((address_space(1))) void*)gp,
                (__attribute__((address_space(3))) void*)lp, 16, 0, 0);
        }
        __syncthreads();   // drains vmcnt -> LDS tiles ready

        #pragma unroll
        for (int s = 0; s < 2; ++s) {       // two K=32 MFMA steps per stage
            const int fs = (c16 << 3) | ((4 * s + quad + (c16 >> 1)) & 7);
            bf16x8 afrag[4], bfrag[4];
            #pragma unroll
            for (int t = 0; t < 4; ++t) {
                afrag[t] = *(const bf16x8*)(smem + (wm * 4 + t) * 1024 + fs * 8);
                bfrag[t] = *(const bf16x8*)(smem + 8192 + (wn * 4 + t) * 1024 + fs * 8);
            }
            #pragma unroll
            for (int tm = 0; tm < 4; ++tm)
                #pragma unroll
                for (int tn = 0; tn < 4; ++tn)
                    acc[tm][tn] = __builtin_amdgcn_mfma_f32_16x16x32_bf16(
                        afrag[tm], bfrag[tn], acc[tm][tn], 0, 0, 0);
        }
        __syncthreads();   // protect LDS before next stage overwrites
    }

    // ---- epilogue: column partial sums ----
    // C/D layout: col = c16, row = quad*4 + r   [measured m89/m91]
    float sqi[4][4];
    #pragma unroll
    for (int tm = 0; tm < 4; ++tm)
        #pragma unroll
        for (int r = 0; r < 4; ++r)
            sqi[tm][r] = sq[i0 + wm * 64 + tm * 16 + quad * 4 + r];
    float sqj[4];
    #pragma unroll
    for (int tn = 0; tn < 4; ++tn)
        sqj[tn] = sq[j0 + wn * 64 + tn * 16 + c16];

    float cpa[4], cna[4], cpb[4], cnb[4], cpd[4], cnd[4];
    const bool diag = (bi == bj);   // same-class pairs only occur here (8 | 128)

    #pragma unroll
    for (int tn = 0; tn < 4; ++tn) {
        float pa = 0.f, na = 0.f, pb = 0.f, nb = 0.f, pd = 0.f, nd = 0.f;
        if (!diag) {
            // pure negatives: branch-free
            #pragma unroll
            for (int tm = 0; tm < 4; ++tm)
                #pragma unroll
                for (int r = 0; r < 4; ++r) {
                    float dot = acc[tm][tn][r];
                    float dsq = sqi[tm][r] + sqj[tn] - 2.0f * dot;
                    float dist = sqrtf(fmaxf(dsq, 1e-12f));
                    float t = __expf(20.0f * (1.1f - dist));   // exp(BETA(1.1-d))
                    na = fmaf(t, t, na);                        // e^4 * exp(40(1-d))
                    nb += t;
                    nd += dist;
                }
        } else {
            const int gj = j0 + wn * 64 + tn * 16 + c16;
            const int gjc = gj >> 3;
            #pragma unroll
            for (int tm = 0; tm < 4; ++tm)
                #pragma unroll
                for (int r = 0; r < 4; ++r) {
                    const int gi = i0 + wm * 64 + tm * 16 + quad * 4 + r;
                    float dot = acc[tm][tn][r];
                    float dsq = sqi[tm][r] + sqj[tn] - 2.0f * dot;
                    float dist = sqrtf(fmaxf(dsq, 1e-12f));
                    float t = __expf(20.0f * (1.1f - dist));
                    bool same = (gi >> 3) == gjc;
                    if (same) {
                        if (gi != gj) {
                            pa = fmaf(t, t, pa);
                            pb += __expf(20.0f * (dist - 0.8f));
                            pd += dist;
                        }
                    } else {
                        na = fmaf(t, t, na);
                        nb += t;
                        nd += dist;
                    }
                }
        }
        cpa[tn] = pa; cna[tn] = na; cpb[tn] = pb;
        cnb[tn] = nb; cpd[tn] = pd; cnd[tn] = nd;
    }

    // reduce the 4 quads (each column's 64 rows): lanes ^16, ^32 only
    #pragma unroll
    for (int tn = 0; tn < 4; ++tn) {
        #pragma unroll
        for (int s = 16; s < 64; s <<= 1) {
            cna[tn] += __shfl_xor(cna[tn], s);
            cnb[tn] += __shfl_xor(cnb[tn], s);
            cnd[tn] += __shfl_xor(cnd[tn], s);
        }
        if (diag) {
            #pragma unroll
            for (int s = 16; s < 64; s <<= 1) {
                cpa[tn] += __shfl_xor(cpa[tn], s);
                cpb[tn] += __shfl_xor(cpb[tn], s);
                cpd[tn] += __shfl_xor(cpd[tn], s);
            }
        }
    }

    // combine the two wm halves via LDS (smem is free after last barrier)
    float* colBuf = (float*)smem;   // [2][128][6] floats = 6 KB
    #pragma unroll
    for (int tn = 0; tn < 4; ++tn) {
        // all 4 quads hold identical reduced values; same-addr same-value writes
        int cb = (wm * 128 + wn * 64 + tn * 16 + c16) * 6;
        colBuf[cb + 0] = cpa[tn]; colBuf[cb + 1] = cna[tn];
        colBuf[cb + 2] = cpb[tn]; colBuf[cb + 3] = cnb[tn];
        colBuf[cb + 4] = cpd[tn]; colBuf[cb + 5] = cnd[tn];
    }
    __syncthreads();

    // atomic-free partial store: contiguous 3 KB per block
    float* dst = colPart + (size_t)bi * N * 6 + (size_t)j0 * 6;
    #pragma unroll
    for (int it = 0; it < 3; ++it) {
        int idx = it * 256 + tid;               // 0..767
        dst[idx] = colBuf[idx] + colBuf[768 + idx];
    }
}

// ---------------------------------------------------------------------------
// Kernel 3: reduce the 32 per-block partial slots -> per-row loss pieces,
// then block-reduce and atomically accumulate the 3 global means into out.
// (out zero-initialized by prep_kernel; stream serialization guarantees order)
// ---------------------------------------------------------------------------
__global__ __launch_bounds__(256) void reduce_finalize(const float* __restrict__ colPart,
                                                       float* __restrict__ out) {
    int j = blockIdx.x * 256 + threadIdx.x;     // 4096 threads total
    float pa = 0.f, na = 0.f, pb = 0.f, nb = 0.f, pd = 0.f, nd = 0.f;
    for (int s = 0; s < NSLOT; ++s) {
        const float* p = colPart + (size_t)s * N * 6 + (size_t)j * 6;
        pa += p[0]; na += p[1]; pb += p[2];
        nb += p[3]; pd += p[4]; nd += p[5];
    }
    // pa/na both carry the same e^4 factor vs exp(40(1-d)) -> cancels in a_lr
    float a_lr = 1.0f - pa / (pa + na);
    float L = a_lr * (logf(pb) + logf(nb));

    #pragma unroll
    for (int s = 1; s < 64; s <<= 1) {
        L  += __shfl_xor(L, s);
        pd += __shfl_xor(pd, s);
        nd += __shfl_xor(nd, s);
    }
    __shared__ float r0[4], r1[4], r2[4];
    int lane = threadIdx.x & 63, w = threadIdx.x >> 6;
    if (lane == 0) { r0[w] = L; r1[w] = pd; r2[w] = nd; }
    __syncthreads();
    if (threadIdx.x == 0) {
        float Ls = r0[0] + r0[1] + r0[2] + r0[3];
        float Ps = r1[0] + r1[1] + r1[2] + r1[3];
        float Gs = r2[0] + r2[1] + r2[2] + r2[3];
        atomicAdd(out + 0, Ls / (float)N);
        atomicAdd(out + 2, Ps / ((float)N * 7.0f));              // 7 pos pairs/row
        atomicAdd(out + 3, Gs / ((float)N * (float)(N - 8)));    // 4088 neg/row
        // out[1] (accuracy) stays 0 from prep's init
    }
}

// ---------------------------------------------------------------------------
extern "C" void kernel_launch(void* const* d_in, const int* in_sizes, int n_in,
                              void* d_out, int out_size, void* d_ws, size_t ws_size,
                              hipStream_t stream) {
    const float* x = (const float*)d_in[0];
    float* out = (float*)d_out;
    char* ws = (char*)d_ws;

    ushort* xb      = (ushort*)ws;                                   // 8 MB bf16 matrix
    float*  sq      = (float*)(ws + (size_t)N * D * 2);              // 16 KB row norms
    float*  colPart = (float*)(ws + (size_t)N * D * 2 + N * 4);      // 3 MB partials

    prep_kernel<<<N / 4, 256, 0, stream>>>(x, xb, sq, out);

    dim3 grid(N / BN, N / BM);
    gemm_fused<<<grid, 256, 0, stream>>>(xb, sq, colPart);

    reduce_finalize<<<N / 256, 256, 0, stream>>>(colPart, out);
}

// Round 9
// 103.939 us; speedup vs baseline: 1.5109x; 1.0464x over previous
//
#include <hip/hip_runtime.h>

#define N 4096
#define D 1024
#define BM 128
#define BN 128
#define BKB 128     // K-bytes (= fp8 elements) per stage
#define NSLOT 32    // N / BM partial-slots per column

typedef float floatx4 __attribute__((ext_vector_type(4)));
typedef long long i64;

// ---------------------------------------------------------------------------
// Kernel 1: fp32 -> fp8 e4m3 (scaled x32; pow2 -> exact to undo) + row norms.
// One wave per row. Thread (0,0) zero-inits d_out for the atomic finalize.
// ---------------------------------------------------------------------------
__global__ __launch_bounds__(256) void prep_kernel(const float* __restrict__ x,
                                                   unsigned char* __restrict__ xq,
                                                   float* __restrict__ sq,
                                                   float* __restrict__ out) {
    if (blockIdx.x == 0 && threadIdx.x == 0) {
        out[0] = 0.f; out[1] = 0.f; out[2] = 0.f; out[3] = 0.f;
    }
    int row = blockIdx.x * 4 + (threadIdx.x >> 6);
    int lane = threadIdx.x & 63;
    const float4* xr = (const float4*)(x + (size_t)row * D);
    unsigned int* qr = (unsigned int*)(xq + (size_t)row * D);
    float s = 0.f;
    #pragma unroll
    for (int j = 0; j < 4; ++j) {
        float4 v = xr[j * 64 + lane];
        s += v.x * v.x + v.y * v.y + v.z * v.z + v.w * v.w;
        // OCP e4m3 pack, values scaled by 32 (sigma ~1.0, no subnormals)
        unsigned int w = __builtin_amdgcn_cvt_pk_fp8_f32(v.x * 32.f, v.y * 32.f, 0, false);
        w = __builtin_amdgcn_cvt_pk_fp8_f32(v.z * 32.f, v.w * 32.f, w, true);
        qr[j * 64 + lane] = w;
    }
    #pragma unroll
    for (int sh = 1; sh < 64; sh <<= 1) s += __shfl_xor(s, sh);
    if (lane == 0) sq[row] = s;
}

// ---------------------------------------------------------------------------
// Kernel 2: fused X.X^T GEMM in fp8 e4m3 (16x16x32 fp8 MFMA, = bf16 rate but
// half the bytes) + dist + masked exp COLUMN-reductions.
// BKB=128 fp8 elems/stage: 8 K-stages (vs 16 in bf16-BK64), 64 MFMA/barrier.
// LDS: 2KB group = 16 rows x 128B; slot16 s holds (r = s>>3,
// kc16 = ((s&7)-(r&7))&7):
//  (a) staging quarter-waves cover 2 full 128B rows (coalesced)
//  (b) fragment ds_read_b64 sweeps 8 bank-pair residues 2x (2-way = free)
// dot_real = acc * 2^-10 (undo the x32 input scaling exactly).
// ---------------------------------------------------------------------------
__global__ __launch_bounds__(256, 2) void gemm_fused(const unsigned char* __restrict__ xq,
                                                     const float* __restrict__ sq,
                                                     float* __restrict__ colPart) {
    __shared__ __align__(16) unsigned char smem[2 * BM * BKB];   // 32 KB

    const int bi = blockIdx.y, bj = blockIdx.x;
    const int i0 = bi * BM, j0 = bj * BN;
    const int tid = threadIdx.x;
    const int lane = tid & 63, wave = tid >> 6;
    const int wm = wave >> 1, wn = wave & 1;        // 2x2 waves over 128x128
    const int quad = lane >> 4, c16 = lane & 15;

    // staging source byte offsets (slot = lane position, content per swizzle)
    int goff[8];
    #pragma unroll
    for (int it = 0; it < 8; ++it) {
        int chunk = it * 256 + tid;          // 2048 chunks of 16B
        int half = chunk >> 10;              // 0 = A, 1 = B (wave-uniform)
        int c = chunk & 1023;
        int g = c >> 7, p = c & 127;         // 8 groups of (16 rows x 8 kc16)
        int r = p >> 3;
        int kc = ((p & 7) - (r & 7)) & 7;
        int grow = (half ? j0 : i0) + g * 16 + r;
        goff[it] = grow * D + kc * 16;       // byte offset; += kt per stage
    }

    floatx4 acc[4][4];
    #pragma unroll
    for (int a = 0; a < 4; ++a)
        #pragma unroll
        for (int b = 0; b < 4; ++b) acc[a][b] = (floatx4){0.f, 0.f, 0.f, 0.f};

    for (int kt = 0; kt < D; kt += BKB) {    // 8 stages
        #pragma unroll
        for (int it = 0; it < 8; ++it) {
            const unsigned char* gp = xq + goff[it] + kt;
            unsigned char* lp = smem + (it * 256 + tid) * 16;
            __builtin_amdgcn_global_load_lds(
                (const __attribute__((address_space(1))) void*)gp,
                (__attribute__((address_space(3))) void*)lp, 16, 0, 0);
        }
        __syncthreads();   // drains vmcnt -> LDS tiles ready

        #pragma unroll
        for (int s = 0; s < 4; ++s) {        // four K=32 fp8 MFMA steps
            const int kc16 = 2 * s + (quad >> 1);
            const int sub = quad & 1;
            const int fb = ((kc16 + (c16 & 7)) & 7) * 16 + sub * 8 + c16 * 128;
            i64 afrag[4], bfrag[4];
            #pragma unroll
            for (int t = 0; t < 4; ++t) {
                afrag[t] = *(const i64*)(smem + (wm * 4 + t) * 2048 + fb);
                bfrag[t] = *(const i64*)(smem + 16384 + (wn * 4 + t) * 2048 + fb);
            }
            #pragma unroll
            for (int tm = 0; tm < 4; ++tm)
                #pragma unroll
                for (int tn = 0; tn < 4; ++tn)
                    acc[tm][tn] = __builtin_amdgcn_mfma_f32_16x16x32_fp8_fp8(
                        afrag[tm], bfrag[tn], acc[tm][tn], 0, 0, 0);
        }
        __syncthreads();   // protect LDS before next stage overwrites
    }

    // ---- epilogue: column partial sums ----
    // C/D layout: col = c16, row = quad*4 + r   [measured m89/m91]
    float sqi[4][4];
    #pragma unroll
    for (int tm = 0; tm < 4; ++tm)
        #pragma unroll
        for (int r = 0; r < 4; ++r)
            sqi[tm][r] = sq[i0 + wm * 64 + tm * 16 + quad * 4 + r];
    float sqj[4];
    #pragma unroll
    for (int tn = 0; tn < 4; ++tn)
        sqj[tn] = sq[j0 + wn * 64 + tn * 16 + c16];

    float cpa[4], cna[4], cpb[4], cnb[4], cpd[4], cnd[4];
    const bool diag = (bi == bj);   // same-class pairs only occur here (8 | 128)
    const float DS = -0.001953125f; // -2 * 2^-10: undo x32 input scaling

    #pragma unroll
    for (int tn = 0; tn < 4; ++tn) {
        float pa = 0.f, na = 0.f, pb = 0.f, nb = 0.f, pd = 0.f, nd = 0.f;
        if (!diag) {
            // pure negatives: branch-free
            #pragma unroll
            for (int tm = 0; tm < 4; ++tm)
                #pragma unroll
                for (int r = 0; r < 4; ++r) {
                    float dot = acc[tm][tn][r];
                    float dsq = fmaf(dot, DS, sqi[tm][r] + sqj[tn]);
                    float dist = sqrtf(fmaxf(dsq, 1e-12f));
                    float t = __expf(20.0f * (1.1f - dist));   // exp(BETA(1.1-d))
                    na = fmaf(t, t, na);                        // e^4 * exp(40(1-d))
                    nb += t;
                    nd += dist;
                }
        } else {
            const int gj = j0 + wn * 64 + tn * 16 + c16;
            const int gjc = gj >> 3;
            #pragma unroll
            for (int tm = 0; tm < 4; ++tm)
                #pragma unroll
                for (int r = 0; r < 4; ++r) {
                    const int gi = i0 + wm * 64 + tm * 16 + quad * 4 + r;
                    float dot = acc[tm][tn][r];
                    float dsq = fmaf(dot, DS, sqi[tm][r] + sqj[tn]);
                    float dist = sqrtf(fmaxf(dsq, 1e-12f));
                    float t = __expf(20.0f * (1.1f - dist));
                    bool same = (gi >> 3) == gjc;
                    if (same) {
                        if (gi != gj) {
                            pa = fmaf(t, t, pa);
                            pb += __expf(20.0f * (dist - 0.8f));
                            pd += dist;
                        }
                    } else {
                        na = fmaf(t, t, na);
                        nb += t;
                        nd += dist;
                    }
                }
        }
        cpa[tn] = pa; cna[tn] = na; cpb[tn] = pb;
        cnb[tn] = nb; cpd[tn] = pd; cnd[tn] = nd;
    }

    // reduce the 4 quads (each column's 64 rows): lanes ^16, ^32 only
    #pragma unroll
    for (int tn = 0; tn < 4; ++tn) {
        #pragma unroll
        for (int s = 16; s < 64; s <<= 1) {
            cna[tn] += __shfl_xor(cna[tn], s);
            cnb[tn] += __shfl_xor(cnb[tn], s);
            cnd[tn] += __shfl_xor(cnd[tn], s);
        }
        if (diag) {
            #pragma unroll
            for (int s = 16; s < 64; s <<= 1) {
                cpa[tn] += __shfl_xor(cpa[tn], s);
                cpb[tn] += __shfl_xor(cpb[tn], s);
                cpd[tn] += __shfl_xor(cpd[tn], s);
            }
        }
    }

    // combine the two wm halves via LDS (smem is free after last barrier)
    float* colBuf = (float*)smem;   // [2][128][6] floats = 6 KB
    #pragma unroll
    for (int tn = 0; tn < 4; ++tn) {
        // all 4 quads hold identical reduced values; same-addr same-value writes
        int cb = (wm * 128 + wn * 64 + tn * 16 + c16) * 6;
        colBuf[cb + 0] = cpa[tn]; colBuf[cb + 1] = cna[tn];
        colBuf[cb + 2] = cpb[tn]; colBuf[cb + 3] = cnb[tn];
        colBuf[cb + 4] = cpd[tn]; colBuf[cb + 5] = cnd[tn];
    }
    __syncthreads();

    // atomic-free partial store: contiguous 3 KB per block
    float* dst = colPart + (size_t)bi * N * 6 + (size_t)j0 * 6;
    #pragma unroll
    for (int it = 0; it < 3; ++it) {
        int idx = it * 256 + tid;               // 0..767
        dst[idx] = colBuf[idx] + colBuf[768 + idx];
    }
}

// ---------------------------------------------------------------------------
// Kernel 3: reduce the 32 per-block partial slots -> per-row loss pieces,
// then block-reduce and atomically accumulate the 3 global means into out.
// (out zero-initialized by prep_kernel; stream serialization guarantees order)
// ---------------------------------------------------------------------------
__global__ __launch_bounds__(256) void reduce_finalize(const float* __restrict__ colPart,
                                                       float* __restrict__ out) {
    int j = blockIdx.x * 256 + threadIdx.x;     // 4096 threads total
    float pa = 0.f, na = 0.f, pb = 0.f, nb = 0.f, pd = 0.f, nd = 0.f;
    for (int s = 0; s < NSLOT; ++s) {
        const float* p = colPart + (size_t)s * N * 6 + (size_t)j * 6;
        pa += p[0]; na += p[1]; pb += p[2];
        nb += p[3]; pd += p[4]; nd += p[5];
    }
    // pa/na both carry the same e^4 factor vs exp(40(1-d)) -> cancels in a_lr
    float a_lr = 1.0f - pa / (pa + na);
    float L = a_lr * (logf(pb) + logf(nb));

    #pragma unroll
    for (int s = 1; s < 64; s <<= 1) {
        L  += __shfl_xor(L, s);
        pd += __shfl_xor(pd, s);
        nd += __shfl_xor(nd, s);
    }
    __shared__ float r0[4], r1[4], r2[4];
    int lane = threadIdx.x & 63, w = threadIdx.x >> 6;
    if (lane == 0) { r0[w] = L; r1[w] = pd; r2[w] = nd; }
    __syncthreads();
    if (threadIdx.x == 0) {
        float Ls = r0[0] + r0[1] + r0[2] + r0[3];
        float Ps = r1[0] + r1[1] + r1[2] + r1[3];
        float Gs = r2[0] + r2[1] + r2[2] + r2[3];
        atomicAdd(out + 0, Ls / (float)N);
        atomicAdd(out + 2, Ps / ((float)N * 7.0f));              // 7 pos pairs/row
        atomicAdd(out + 3, Gs / ((float)N * (float)(N - 8)));    // 4088 neg/row
        // out[1] (accuracy) stays 0 from prep's init
    }
}

// ---------------------------------------------------------------------------
extern "C" void kernel_launch(void* const* d_in, const int* in_sizes, int n_in,
                              void* d_out, int out_size, void* d_ws, size_t ws_size,
                              hipStream_t stream) {
    const float* x = (const float*)d_in[0];
    float* out = (float*)d_out;
    char* ws = (char*)d_ws;

    unsigned char* xq = (unsigned char*)ws;                          // 4 MB fp8 matrix
    float* sq         = (float*)(ws + (size_t)N * D);                // 16 KB row norms
    float* colPart    = (float*)(ws + (size_t)N * D + N * 4);        // 3 MB partials

    prep_kernel<<<N / 4, 256, 0, stream>>>(x, xq, sq, out);

    dim3 grid(N / BN, N / BM);
    gemm_fused<<<grid, 256, 0, stream>>>(xq, sq, colPart);

    reduce_finalize<<<N / 256, 256, 0, stream>>>(colPart, out);
}

// Round 10
// 101.330 us; speedup vs baseline: 1.5498x; 1.0257x over previous
//
#include <hip/hip_runtime.h>

#define N 4096
#define D 1024
#define BM 128
#define BN 128
#define BKB 128     // K-bytes (= fp8 elements) per stage = one MX K-window
#define NSLOT 32    // N / BM partial-slots per column

typedef float floatx4 __attribute__((ext_vector_type(4)));
typedef int intx8 __attribute__((ext_vector_type(8)));
union frag8 { intx8 v; int4 q[2]; };

// ---------------------------------------------------------------------------
// Kernel 1: fp32 -> fp8 e4m3 (scaled x32; pow2 -> exact to undo) + row norms.
// One wave per row. Thread (0,0) zero-inits d_out for the atomic finalize.
// ---------------------------------------------------------------------------
__global__ __launch_bounds__(256) void prep_kernel(const float* __restrict__ x,
                                                   unsigned char* __restrict__ xq,
                                                   float* __restrict__ sq,
                                                   float* __restrict__ out) {
    if (blockIdx.x == 0 && threadIdx.x == 0) {
        out[0] = 0.f; out[1] = 0.f; out[2] = 0.f; out[3] = 0.f;
    }
    int row = blockIdx.x * 4 + (threadIdx.x >> 6);
    int lane = threadIdx.x & 63;
    const float4* xr = (const float4*)(x + (size_t)row * D);
    unsigned int* qr = (unsigned int*)(xq + (size_t)row * D);
    float s = 0.f;
    #pragma unroll
    for (int j = 0; j < 4; ++j) {
        float4 v = xr[j * 64 + lane];
        s += v.x * v.x + v.y * v.y + v.z * v.z + v.w * v.w;
        // OCP e4m3 pack, values scaled by 32 (sigma ~1.0, no subnormals)
        unsigned int w = __builtin_amdgcn_cvt_pk_fp8_f32(v.x * 32.f, v.y * 32.f, 0, false);
        w = __builtin_amdgcn_cvt_pk_fp8_f32(v.z * 32.f, v.w * 32.f, w, true);
        qr[j * 64 + lane] = w;
    }
    #pragma unroll
    for (int sh = 1; sh < 64; sh <<= 1) s += __shfl_xor(s, sh);
    if (lane == 0) sq[row] = s;
}

// ---------------------------------------------------------------------------
// Kernel 2: fused X.X^T GEMM via MX-scaled fp8 MFMA (16x16x128 f8f6f4,
// scales fixed at 1.0 = 0x7f7f7f7f so opsel/scale mapping is irrelevant)
// + dist + masked exp COLUMN-reductions.
// K=128 per instruction: 128 MFMAs/wave total (4x fewer than R9, 2x rate).
// A and B share one LDS layout; X.X^T symmetry means any internal k-byte
// permutation of the instruction cancels between the two operands.
// LDS: 2KB group = 16 rows x 8 chunks(16B); chunk c of row r stored at slot
// c ^ (r&7):
//  (a) staging quarter-waves = 2 rows x 8 chunks = full 128B segments
//  (b) fragment ds_read_b128 (lane reads chunks 2*quad, 2*quad+1 of row c16)
//      hits all 32 banks at the 8-words/bank floor (conflict-free)
// dot_real = acc * 2^-10 (undo the x32 input scaling exactly).
// ---------------------------------------------------------------------------
__global__ __launch_bounds__(256, 2) void gemm_fused(const unsigned char* __restrict__ xq,
                                                     const float* __restrict__ sq,
                                                     float* __restrict__ colPart) {
    __shared__ __align__(16) unsigned char smem[2 * BM * BKB];   // 32 KB

    const int bi = blockIdx.y, bj = blockIdx.x;
    const int i0 = bi * BM, j0 = bj * BN;
    const int tid = threadIdx.x;
    const int lane = tid & 63, wave = tid >> 6;
    const int wm = wave >> 1, wn = wave & 1;        // 2x2 waves over 128x128
    const int quad = lane >> 4, c16 = lane & 15;

    // staging source byte offsets (slot = lane position, content per swizzle)
    int goff[8];
    #pragma unroll
    for (int it = 0; it < 8; ++it) {
        int chunk = it * 256 + tid;          // 2048 chunks of 16B
        int half = chunk >> 10;              // 0 = A, 1 = B (wave-uniform)
        int c = chunk & 1023;
        int g = c >> 7, s = c & 127;         // 8 groups of (16 rows x 8 chunks)
        int r = s >> 3, ch = s & 7;
        int grow = (half ? j0 : i0) + g * 16 + r;
        goff[it] = grow * D + ((ch ^ (r & 7)) << 4);   // byte offset; += kt
    }
    // fragment LDS offsets: lane reads chunks 2*quad, 2*quad+1 of row c16
    const int rowb = c16 * 128;
    const int fo0 = ((2 * quad + 0) ^ (c16 & 7)) * 16;
    const int fo1 = ((2 * quad + 1) ^ (c16 & 7)) * 16;

    floatx4 acc[4][4];
    #pragma unroll
    for (int a = 0; a < 4; ++a)
        #pragma unroll
        for (int b = 0; b < 4; ++b) acc[a][b] = (floatx4){0.f, 0.f, 0.f, 0.f};

    for (int kt = 0; kt < D; kt += BKB) {    // 8 stages
        #pragma unroll
        for (int it = 0; it < 8; ++it) {
            const unsigned char* gp = xq + goff[it] + kt;
            unsigned char* lp = smem + (it * 256 + tid) * 16;
            __builtin_amdgcn_global_load_lds(
                (const __attribute__((address_space(1))) void*)gp,
                (__attribute__((address_space(3))) void*)lp, 16, 0, 0);
        }
        __syncthreads();   // drains vmcnt -> LDS tiles ready

        frag8 bf[4];
        #pragma unroll
        for (int tn = 0; tn < 4; ++tn) {
            const unsigned char* bp = smem + 16384 + (wn * 4 + tn) * 2048 + rowb;
            bf[tn].q[0] = *(const int4*)(bp + fo0);
            bf[tn].q[1] = *(const int4*)(bp + fo1);
        }
        #pragma unroll
        for (int tm = 0; tm < 4; ++tm) {
            const unsigned char* ap = smem + (wm * 4 + tm) * 2048 + rowb;
            frag8 af;
            af.q[0] = *(const int4*)(ap + fo0);
            af.q[1] = *(const int4*)(ap + fo1);
            #pragma unroll
            for (int tn = 0; tn < 4; ++tn)
                acc[tm][tn] = __builtin_amdgcn_mfma_scale_f32_16x16x128_f8f6f4(
                    af.v, bf[tn].v, acc[tm][tn],
                    0, 0,                    // cbsz/blgp: fp8 e4m3 A and B
                    0, 0x7f7f7f7f,           // opsel_a, scale_a = 1.0 (E8M0 127)
                    0, 0x7f7f7f7f);          // opsel_b, scale_b = 1.0
        }
        __syncthreads();   // protect LDS before next stage overwrites
    }

    // ---- epilogue: column partial sums ----
    // C/D layout shape-determined: col = c16, row = quad*4 + r  [m89/m127/m128]
    float sqi[4][4];
    #pragma unroll
    for (int tm = 0; tm < 4; ++tm)
        #pragma unroll
        for (int r = 0; r < 4; ++r)
            sqi[tm][r] = sq[i0 + wm * 64 + tm * 16 + quad * 4 + r];
    float sqj[4];
    #pragma unroll
    for (int tn = 0; tn < 4; ++tn)
        sqj[tn] = sq[j0 + wn * 64 + tn * 16 + c16];

    float cpa[4], cna[4], cpb[4], cnb[4], cpd[4], cnd[4];
    const bool diag = (bi == bj);   // same-class pairs only occur here (8 | 128)
    const float DS = -0.001953125f; // -2 * 2^-10: undo x32 input scaling

    #pragma unroll
    for (int tn = 0; tn < 4; ++tn) {
        float pa = 0.f, na = 0.f, pb = 0.f, nb = 0.f, pd = 0.f, nd = 0.f;
        if (!diag) {
            // pure negatives: branch-free
            #pragma unroll
            for (int tm = 0; tm < 4; ++tm)
                #pragma unroll
                for (int r = 0; r < 4; ++r) {
                    float dot = acc[tm][tn][r];
                    float dsq = fmaf(dot, DS, sqi[tm][r] + sqj[tn]);
                    float dist = sqrtf(fmaxf(dsq, 1e-12f));
                    float t = __expf(20.0f * (1.1f - dist));   // exp(BETA(1.1-d))
                    na = fmaf(t, t, na);                        // e^4 * exp(40(1-d))
                    nb += t;
                    nd += dist;
                }
        } else {
            const int gj = j0 + wn * 64 + tn * 16 + c16;
            const int gjc = gj >> 3;
            #pragma unroll
            for (int tm = 0; tm < 4; ++tm)
                #pragma unroll
                for (int r = 0; r < 4; ++r) {
                    const int gi = i0 + wm * 64 + tm * 16 + quad * 4 + r;
                    float dot = acc[tm][tn][r];
                    float dsq = fmaf(dot, DS, sqi[tm][r] + sqj[tn]);
                    float dist = sqrtf(fmaxf(dsq, 1e-12f));
                    float t = __expf(20.0f * (1.1f - dist));
                    bool same = (gi >> 3) == gjc;
                    if (same) {
                        if (gi != gj) {
                            pa = fmaf(t, t, pa);
                            pb += __expf(20.0f * (dist - 0.8f));
                            pd += dist;
                        }
                    } else {
                        na = fmaf(t, t, na);
                        nb += t;
                        nd += dist;
                    }
                }
        }
        cpa[tn] = pa; cna[tn] = na; cpb[tn] = pb;
        cnb[tn] = nb; cpd[tn] = pd; cnd[tn] = nd;
    }

    // reduce the 4 quads (each column's 64 rows): lanes ^16, ^32 only
    #pragma unroll
    for (int tn = 0; tn < 4; ++tn) {
        #pragma unroll
        for (int s = 16; s < 64; s <<= 1) {
            cna[tn] += __shfl_xor(cna[tn], s);
            cnb[tn] += __shfl_xor(cnb[tn], s);
            cnd[tn] += __shfl_xor(cnd[tn], s);
        }
        if (diag) {
            #pragma unroll
            for (int s = 16; s < 64; s <<= 1) {
                cpa[tn] += __shfl_xor(cpa[tn], s);
                cpb[tn] += __shfl_xor(cpb[tn], s);
                cpd[tn] += __shfl_xor(cpd[tn], s);
            }
        }
    }

    // combine the two wm halves via LDS (smem is free after last barrier)
    float* colBuf = (float*)smem;   // [2][128][6] floats = 6 KB
    #pragma unroll
    for (int tn = 0; tn < 4; ++tn) {
        // all 4 quads hold identical reduced values; same-addr same-value writes
        int cb = (wm * 128 + wn * 64 + tn * 16 + c16) * 6;
        colBuf[cb + 0] = cpa[tn]; colBuf[cb + 1] = cna[tn];
        colBuf[cb + 2] = cpb[tn]; colBuf[cb + 3] = cnb[tn];
        colBuf[cb + 4] = cpd[tn]; colBuf[cb + 5] = cnd[tn];
    }
    __syncthreads();

    // atomic-free partial store: contiguous 3 KB per block
    float* dst = colPart + (size_t)bi * N * 6 + (size_t)j0 * 6;
    #pragma unroll
    for (int it = 0; it < 3; ++it) {
        int idx = it * 256 + tid;               // 0..767
        dst[idx] = colBuf[idx] + colBuf[768 + idx];
    }
}

// ---------------------------------------------------------------------------
// Kernel 3: reduce the 32 per-block partial slots -> per-row loss pieces,
// then block-reduce and atomically accumulate the 3 global means into out.
// (out zero-initialized by prep_kernel; stream serialization guarantees order)
// ---------------------------------------------------------------------------
__global__ __launch_bounds__(256) void reduce_finalize(const float* __restrict__ colPart,
                                                       float* __restrict__ out) {
    int j = blockIdx.x * 256 + threadIdx.x;     // 4096 threads total
    float pa = 0.f, na = 0.f, pb = 0.f, nb = 0.f, pd = 0.f, nd = 0.f;
    for (int s = 0; s < NSLOT; ++s) {
        const float* p = colPart + (size_t)s * N * 6 + (size_t)j * 6;
        pa += p[0]; na += p[1]; pb += p[2];
        nb += p[3]; pd += p[4]; nd += p[5];
    }
    // pa/na both carry the same e^4 factor vs exp(40(1-d)) -> cancels in a_lr
    float a_lr = 1.0f - pa / (pa + na);
    float L = a_lr * (logf(pb) + logf(nb));

    #pragma unroll
    for (int s = 1; s < 64; s <<= 1) {
        L  += __shfl_xor(L, s);
        pd += __shfl_xor(pd, s);
        nd += __shfl_xor(nd, s);
    }
    __shared__ float r0[4], r1[4], r2[4];
    int lane = threadIdx.x & 63, w = threadIdx.x >> 6;
    if (lane == 0) { r0[w] = L; r1[w] = pd; r2[w] = nd; }
    __syncthreads();
    if (threadIdx.x == 0) {
        float Ls = r0[0] + r0[1] + r0[2] + r0[3];
        float Ps = r1[0] + r1[1] + r1[2] + r1[3];
        float Gs = r2[0] + r2[1] + r2[2] + r2[3];
        atomicAdd(out + 0, Ls / (float)N);
        atomicAdd(out + 2, Ps / ((float)N * 7.0f));              // 7 pos pairs/row
        atomicAdd(out + 3, Gs / ((float)N * (float)(N - 8)));    // 4088 neg/row
        // out[1] (accuracy) stays 0 from prep's init
    }
}

// ---------------------------------------------------------------------------
extern "C" void kernel_launch(void* const* d_in, const int* in_sizes, int n_in,
                              void* d_out, int out_size, void* d_ws, size_t ws_size,
                              hipStream_t stream) {
    const float* x = (const float*)d_in[0];
    float* out = (float*)d_out;
    char* ws = (char*)d_ws;

    unsigned char* xq = (unsigned char*)ws;                          // 4 MB fp8 matrix
    float* sq         = (float*)(ws + (size_t)N * D);                // 16 KB row norms
    float* colPart    = (float*)(ws + (size_t)N * D + N * 4);        // 3 MB partials

    prep_kernel<<<N / 4, 256, 0, stream>>>(x, xq, sq, out);

    dim3 grid(N / BN, N / BM);
    gemm_fused<<<grid, 256, 0, stream>>>(xq, sq, colPart);

    reduce_finalize<<<N / 256, 256, 0, stream>>>(colPart, out);
}